// Round 8
// baseline (180.955 us; speedup 1.0000x reference)
//
#include <hip/hip_runtime.h>
#include <hip/hip_bf16.h>
#include <cstdint>

typedef __bf16 bf16x8 __attribute__((ext_vector_type(8)));
typedef float f32x4 __attribute__((ext_vector_type(4)));

#define E_DIM 256
#define H_DIM 512
#define TSTR 260   // padded f32 row stride (1040 B: 16B-aligned rows, odd 16B-groups)

// ---------------- kernel 1: W1 (all 3 blocks) -> bf16 chunk-major [mat][c][h][kk] ----------------
__global__ __launch_bounds__(256)
void w1conv_kernel(const float* __restrict__ W1, __bf16* __restrict__ W1cc) {
    int u = blockIdx.x * 256 + threadIdx.x;   // 0..49151
    int j   = u & 3;
    int h   = (u >> 2) & 511;
    int c   = (u >> 11) & 7;
    int mat = u >> 14;                        // 0..2
    bf16x8 v;
#pragma unroll
    for (int i = 0; i < 8; ++i)
        v[i] = (__bf16)W1[(size_t)(mat * 256 + c * 32 + j * 8 + i) * H_DIM + h];
    *(bf16x8*)(W1cc + ((size_t)(mat * 8 + c) * 512 + h) * 32 + j * 8) = v;
}

// ---------------- kernel 2: P = norm(t)@W1a + b1 ; Q = norm(d)@W1b via bf16 MFMA ----------------
// 128 blocks x 512 thr. Block = 32 rows x 256 h. Wave covers 32 rows x 32 h.
__global__ __launch_bounds__(512, 4)
void pq_mfma_kernel(const float* __restrict__ track, const float* __restrict__ det,
                    const __bf16* __restrict__ W1cc, const float* __restrict__ b1,
                    float* __restrict__ P, float* __restrict__ Q) {
    __shared__ __align__(16) __bf16 Ash[32 * 256];   // 16 KB
    __shared__ float sclS[32];

    int tid  = threadIdx.x;
    int lane = tid & 63;
    int wave = tid >> 6;
    int lq   = lane >> 4;
    int lc   = lane & 15;

    int blk  = blockIdx.x;
    int mat  = blk >> 6;               // 0 = P(track), 1 = Q(det)
    int rowg = (blk >> 1) & 31;
    int half = blk & 1;
    int r0   = rowg * 32;
    int h0   = half * 256;
    const float* src = mat ? det : track;

#pragma unroll
    for (int i = 0; i < 4; ++i) {
        int row = wave * 4 + i;
        float4 x = ((const float4*)(src + (size_t)(r0 + row) * E_DIM))[lane];
        float ss = x.x*x.x + x.y*x.y + x.z*x.z + x.w*x.w;
#pragma unroll
        for (int off = 32; off > 0; off >>= 1) ss += __shfl_xor(ss, off);
        if (lane == 0) sclS[row] = 1.0f / fmaxf(sqrtf(ss), 1e-12f);
    }
    __syncthreads();

#pragma unroll
    for (int r = 0; r < 2; ++r) {
        int row = r * 16 + lc;
        float st = sclS[row];
        const float* gp = src + (size_t)(r0 + row) * E_DIM + wave * 32 + lq * 8;
        float4 t0 = *(const float4*)gp;
        float4 t1 = *(const float4*)(gp + 4);
        bf16x8 v;
        v[0] = (__bf16)(t0.x * st); v[1] = (__bf16)(t0.y * st);
        v[2] = (__bf16)(t0.z * st); v[3] = (__bf16)(t0.w * st);
        v[4] = (__bf16)(t1.x * st); v[5] = (__bf16)(t1.y * st);
        v[6] = (__bf16)(t1.z * st); v[7] = (__bf16)(t1.w * st);
        *(bf16x8*)&Ash[(size_t)(r * 512 + wave * 64 + lane) * 8] = v;
    }
    __syncthreads();

    const uint4* Wg = (const uint4*)W1cc + (mat ? 16384 : 0);
    int hb = h0 + wave * 32 + lc;
    bf16x8 bwA[2], bwB[2];
#pragma unroll
    for (int ht = 0; ht < 2; ++ht)
        bwA[ht] = __builtin_bit_cast(bf16x8, Wg[(hb + ht * 16) * 4 + lq]);

    f32x4 acc[2][2];
#pragma unroll
    for (int pt = 0; pt < 2; ++pt)
#pragma unroll
        for (int ht = 0; ht < 2; ++ht)
            acc[pt][ht] = (f32x4){0.f, 0.f, 0.f, 0.f};

#pragma unroll
    for (int c = 0; c < 8; ++c) {
        bf16x8* cur = (c & 1) ? bwB : bwA;
        bf16x8* nxt = (c & 1) ? bwA : bwB;
        if (c < 7) {
#pragma unroll
            for (int ht = 0; ht < 2; ++ht)
                nxt[ht] = __builtin_bit_cast(bf16x8, Wg[(c + 1) * 2048 + (hb + ht * 16) * 4 + lq]);
        }
#pragma unroll
        for (int pt = 0; pt < 2; ++pt) {
            bf16x8 af = *(const bf16x8*)&Ash[(size_t)((pt * 8 + c) * 64 + lane) * 8];
#pragma unroll
            for (int ht = 0; ht < 2; ++ht)
                acc[pt][ht] = __builtin_amdgcn_mfma_f32_16x16x32_bf16(cur[ht], af, acc[pt][ht], 0, 0, 0);
        }
    }

    float* dst = mat ? Q : P;
#pragma unroll
    for (int ht = 0; ht < 2; ++ht) {
        int h = h0 + wave * 32 + ht * 16 + lq * 4;
        f32x4 bvv = (f32x4){0.f, 0.f, 0.f, 0.f};
        if (!mat) bvv = *(const f32x4*)&b1[h];
#pragma unroll
        for (int pt = 0; pt < 2; ++pt) {
            f32x4 o = acc[pt][ht] + bvv;
            *(f32x4*)&dst[(size_t)(r0 + pt * 16 + lc) * H_DIM + h] = o;
        }
    }
}

// ---------------- kernel 3: fused pairwise GEMM + LN + SiLU + W2 dot ----------------
// grid 4096 (b, nt16, mt32) x 512 thr (8 waves). Block: 32 pairs (8n x 4m) x 512 H.
// acc = 2pt x 4ht x f32x4 = 32 f32/thread -> zero spill at the (512,4) 128-reg cap.
// B (W1c frags) TRIPLE-buffered in regs (prefetch distance 2) to cover L2 latency at
// 8 MFMA/chunk. A (|t-d| bf16, 32 pairs x 256 K) staged once in LDS, reads base+lane*16.
// Pair = pt*16+lc: n = pt*4 + (lc>>2), m = lc&3. h = wave*64 + ht*16 + lq*4 + rg.
__global__ __launch_bounds__(512, 4)
void main_kernel(const float* __restrict__ track, const float* __restrict__ det,
                 const __bf16* __restrict__ W1cc,
                 const float* __restrict__ P, const float* __restrict__ Q,
                 const float* __restrict__ gamma, const float* __restrict__ beta,
                 const float* __restrict__ W2, const float* __restrict__ b2,
                 float* __restrict__ out) {
    __shared__ __align__(16) char SMEM[28864];
    __bf16* Ash  = (__bf16*)SMEM;                     // [0,16384) phase 1+2
    float*  tsl  = (float*)(SMEM + 16384);            // 8*TSTR f32 [16384,24704)
    float*  dsl  = (float*)(SMEM + 24704);            // 4*TSTR f32 [24704,28864)
    float*  LNr1 = (float*)SMEM;                      // [32][9] phase 2 (Ash dead)
    float*  LNr2 = (float*)(SMEM + 1536);             // [32][9]
    float*  Red2 = (float*)(SMEM + 3072);             // [32][9]
    float*  MuS  = (float*)(SMEM + 4608);             // [32]
    float*  RsS  = (float*)(SMEM + 4736);             // [32]
    __shared__ float sclT[8], sclD[4];

    int tid  = threadIdx.x;
    int lane = tid & 63;
    int wave = tid >> 6;
    int lq   = lane >> 4;
    int lc   = lane & 15;

    int blk = blockIdx.x;
    int b   = blk >> 9;
    int n0  = ((blk >> 5) & 15) * 8;
    int m0  = (blk & 31) * 4;

    // ---- stage loads: wave w -> t-row w; waves 0-3 also -> d-row w
    float4 tstage = ((const float4*)(track + (size_t)(b * 128 + n0 + wave) * E_DIM))[lane];
    float4 dstage;
    if (wave < 4)
        dstage = ((const float4*)(det + (size_t)(b * 128 + m0 + wave) * E_DIM))[lane];

    // ---- W1c frags: prefetch chunks 0 and 1 early (mat 2 base = 32768 uint4)
    const uint4* Wg = (const uint4*)W1cc + 32768;
    int hb = wave * 64 + lc;
    bf16x8 bw[3][4];
#pragma unroll
    for (int ht = 0; ht < 4; ++ht) {
        bw[0][ht] = __builtin_bit_cast(bf16x8, Wg[(hb + ht * 16) * 4 + lq]);
        bw[1][ht] = __builtin_bit_cast(bf16x8, Wg[2048 + (hb + ht * 16) * 4 + lq]);
    }

    // ---- row norms from registers
    {
        float a = tstage.x*tstage.x + tstage.y*tstage.y + tstage.z*tstage.z + tstage.w*tstage.w;
#pragma unroll
        for (int off = 32; off > 0; off >>= 1) a += __shfl_xor(a, off);
        if (lane == 0) sclT[wave] = 1.0f / fmaxf(sqrtf(a), 1e-12f);
    }
    *(float4*)&tsl[wave * TSTR + lane * 4] = tstage;
    if (wave < 4) {
        float d = dstage.x*dstage.x + dstage.y*dstage.y + dstage.z*dstage.z + dstage.w*dstage.w;
#pragma unroll
        for (int off = 32; off > 0; off >>= 1) d += __shfl_xor(d, off);
        if (lane == 0) sclD[wave] = 1.0f / fmaxf(sqrtf(d), 1e-12f);
        *(float4*)&dsl[wave * TSTR + lane * 4] = dstage;
    }
    __syncthreads();

    // ---- A-stage: iter rp covers pair p = rp*16+lc, k = wave*32+lq*8 .. +7
    {
        int k0 = wave * 32 + lq * 8;
        int ml = lc & 3;
        float sd = sclD[ml];
        const float* dr = dsl + ml * TSTR + k0;
        float4 d0 = *(const float4*)dr;
        float4 d1 = *(const float4*)(dr + 4);
#pragma unroll
        for (int rp = 0; rp < 2; ++rp) {
            int nl = rp * 4 + (lc >> 2);
            float st = sclT[nl];
            const float* tr = tsl + nl * TSTR + k0;
            float4 t0 = *(const float4*)tr;
            float4 t1 = *(const float4*)(tr + 4);
            bf16x8 v;
            v[0] = (__bf16)fabsf(t0.x * st - d0.x * sd);
            v[1] = (__bf16)fabsf(t0.y * st - d0.y * sd);
            v[2] = (__bf16)fabsf(t0.z * st - d0.z * sd);
            v[3] = (__bf16)fabsf(t0.w * st - d0.w * sd);
            v[4] = (__bf16)fabsf(t1.x * st - d1.x * sd);
            v[5] = (__bf16)fabsf(t1.y * st - d1.y * sd);
            v[6] = (__bf16)fabsf(t1.z * st - d1.z * sd);
            v[7] = (__bf16)fabsf(t1.w * st - d1.w * sd);
            *(bf16x8*)&Ash[(size_t)(rp * 512 + wave * 64 + lane) * 8] = v;
        }
    }

    // ---- C-init: acc = P[n,h] + Q[m,h] (L2-resident) — fused into MFMA C
    const float* Pb = P + (size_t)(b * 128 + n0) * H_DIM;
    const float* Qb = Q + (size_t)(b * 128 + m0) * H_DIM;
    f32x4 acc[2][4];
    {
        f32x4 qv[4];
#pragma unroll
        for (int ht = 0; ht < 4; ++ht)
            qv[ht] = *(const f32x4*)&Qb[(size_t)(lc & 3) * H_DIM + wave * 64 + ht * 16 + lq * 4];
#pragma unroll
        for (int pt = 0; pt < 2; ++pt) {
            int n = pt * 4 + (lc >> 2);
#pragma unroll
            for (int ht = 0; ht < 4; ++ht) {
                f32x4 pv = *(const f32x4*)&Pb[(size_t)n * H_DIM + wave * 64 + ht * 16 + lq * 4];
                acc[pt][ht] = pv + qv[ht];
            }
        }
    }
    __syncthreads();

    // ---- K-loop: zero barriers; B triple-buffered (distance-2 prefetch)
#pragma unroll
    for (int c = 0; c < 8; ++c) {
        if (c < 6) {
            int nb = (c + 2) % 3;
#pragma unroll
            for (int ht = 0; ht < 4; ++ht)
                bw[nb][ht] = __builtin_bit_cast(bf16x8, Wg[(c + 2) * 2048 + (hb + ht * 16) * 4 + lq]);
        }
        int cur = c % 3;
#pragma unroll
        for (int pt = 0; pt < 2; ++pt) {
            bf16x8 af = *(const bf16x8*)&Ash[(size_t)((pt * 8 + c) * 64 + lane) * 8];
#pragma unroll
            for (int ht = 0; ht < 4; ++ht)
                acc[pt][ht] = __builtin_amdgcn_mfma_f32_16x16x32_bf16(bw[cur][ht], af, acc[pt][ht], 0, 0, 0);
        }
    }

    // ---- phase B: LN partials: in-register sum over 16 h-values, 2 shuffles across lq
#pragma unroll
    for (int pt = 0; pt < 2; ++pt) {
        float s1 = 0.f, s2 = 0.f;
#pragma unroll
        for (int ht = 0; ht < 4; ++ht)
#pragma unroll
            for (int rg = 0; rg < 4; ++rg) {
                float v = acc[pt][ht][rg];
                s1 += v; s2 += v * v;
            }
        s1 += __shfl_xor(s1, 16); s2 += __shfl_xor(s2, 16);
        s1 += __shfl_xor(s1, 32); s2 += __shfl_xor(s2, 32);
        if (lq == 0) {
            LNr1[(pt * 16 + lc) * 9 + wave] = s1;
            LNr2[(pt * 16 + lc) * 9 + wave] = s2;
        }
    }
    __syncthreads();
    if (tid < 32) {
        float S1 = 0.f, S2 = 0.f;
#pragma unroll
        for (int w = 0; w < 8; ++w) { S1 += LNr1[tid * 9 + w]; S2 += LNr2[tid * 9 + w]; }
        float mu = S1 * (1.0f / 512.0f);
        float var = S2 * (1.0f / 512.0f) - mu * mu;
        MuS[tid] = mu;
        RsS[tid] = rsqrtf(var + 1e-5f);
    }
    __syncthreads();

    // ---- phase C: normalize + SiLU + W2 partial dot (per-ht transient param loads)
    float mus[2], rss[2];
#pragma unroll
    for (int pt = 0; pt < 2; ++pt) { mus[pt] = MuS[pt * 16 + lc]; rss[pt] = RsS[pt * 16 + lc]; }
    float ca[2] = {0.f, 0.f};
#pragma unroll
    for (int ht = 0; ht < 4; ++ht) {
        int h = wave * 64 + ht * 16 + lq * 4;
        f32x4 g  = *(const f32x4*)&gamma[h];
        f32x4 bb = *(const f32x4*)&beta[h];
        f32x4 w  = *(const f32x4*)&W2[h];
#pragma unroll
        for (int pt = 0; pt < 2; ++pt) {
#pragma unroll
            for (int rg = 0; rg < 4; ++rg) {
                float x = (acc[pt][ht][rg] - mus[pt]) * rss[pt] * g[rg] + bb[rg];
                float sg = __builtin_amdgcn_rcpf(1.0f + __expf(-x));
                ca[pt] += x * sg * w[rg];
            }
        }
    }
#pragma unroll
    for (int pt = 0; pt < 2; ++pt) {
        float c = ca[pt];
        c += __shfl_xor(c, 16);
        c += __shfl_xor(c, 32);
        if (lq == 0) Red2[(pt * 16 + lc) * 9 + wave] = c;
    }
    __syncthreads();
    if (tid < 32) {
        float o = b2[0];
#pragma unroll
        for (int w = 0; w < 8; ++w) o += Red2[tid * 9 + w];
        int n = n0 + (tid >> 2);
        int m = m0 + (tid & 3);
        out[(size_t)(b * 128 + n) * 128 + m] = o;
    }
}

extern "C" void kernel_launch(void* const* d_in, const int* in_sizes, int n_in,
                              void* d_out, int out_size, void* d_ws, size_t ws_size,
                              hipStream_t stream) {
    const float* track = (const float*)d_in[0];
    const float* det   = (const float*)d_in[1];
    const float* W1    = (const float*)d_in[2];
    const float* b1    = (const float*)d_in[3];
    const float* gamma = (const float*)d_in[4];
    const float* beta  = (const float*)d_in[5];
    const float* W2    = (const float*)d_in[6];
    const float* b2    = (const float*)d_in[7];
    float* out = (float*)d_out;

    char* ws = (char*)d_ws;
    float*  P     = (float*)(ws);                      // 2 MB  (1024 x 512 f32)
    float*  Q     = (float*)(ws + (2u << 20));         // 2 MB
    __bf16* W1cc  = (__bf16*)(ws + (4u << 20));        // 768 KB (bf16 chunk-major, 3 mats)

    w1conv_kernel<<<192, 256, 0, stream>>>(W1, W1cc);
    pq_mfma_kernel<<<128, 512, 0, stream>>>(track, det, W1cc, b1, P, Q);
    main_kernel<<<4096, 512, 0, stream>>>(track, det, W1cc, P, Q, gamma, beta, W2, b2, out);
}

// Round 10
// 152.436 us; speedup vs baseline: 1.1871x; 1.1871x over previous
//
#include <hip/hip_runtime.h>
#include <hip/hip_bf16.h>
#include <cstdint>

typedef __bf16 bf16x8 __attribute__((ext_vector_type(8)));
typedef __bf16 bf16x2 __attribute__((ext_vector_type(2)));
typedef float f32x4 __attribute__((ext_vector_type(4)));

#define E_DIM 256
#define H_DIM 512
#define TSTR 260   // padded f32 row stride (1040 B: 16B-aligned rows, odd 16B-groups)

// packed f32x2 -> bf16x2 (RNE): lowers to v_cvt_pk_bf16_f32 on gfx950
static __device__ __forceinline__ unsigned pkbf(float a, float b) {
    bf16x2 h;
    h[0] = (__bf16)a;
    h[1] = (__bf16)b;
    return __builtin_bit_cast(unsigned, h);
}

// ---------------- kernel 1: W1 (all 3 blocks) -> bf16 chunk-major [mat][c][h][kk] ----------------
__global__ __launch_bounds__(256)
void w1conv_kernel(const float* __restrict__ W1, __bf16* __restrict__ W1cc) {
    int u = blockIdx.x * 256 + threadIdx.x;   // 0..49151
    int j   = u & 3;
    int h   = (u >> 2) & 511;
    int c   = (u >> 11) & 7;
    int mat = u >> 14;                        // 0..2
    const float* src = W1 + (size_t)(mat * 256 + c * 32 + j * 8) * H_DIM + h;
    uint4 v;
    v.x = pkbf(src[0], src[(size_t)1 * H_DIM]);
    v.y = pkbf(src[(size_t)2 * H_DIM], src[(size_t)3 * H_DIM]);
    v.z = pkbf(src[(size_t)4 * H_DIM], src[(size_t)5 * H_DIM]);
    v.w = pkbf(src[(size_t)6 * H_DIM], src[(size_t)7 * H_DIM]);
    *(uint4*)(W1cc + ((size_t)(mat * 8 + c) * 512 + h) * 32 + j * 8) = v;
}

// ---------------- kernel 2: P = norm(t)@W1a + b1 ; Q = norm(d)@W1b via bf16 MFMA ----------------
// 128 blocks x 512 thr. Block = 32 rows x 256 h. Wave covers 32 rows x 32 h.
__global__ __launch_bounds__(512, 4)
void pq_mfma_kernel(const float* __restrict__ track, const float* __restrict__ det,
                    const __bf16* __restrict__ W1cc, const float* __restrict__ b1,
                    float* __restrict__ P, float* __restrict__ Q) {
    __shared__ __align__(16) __bf16 Ash[32 * 256];   // 16 KB
    __shared__ float sclS[32];

    int tid  = threadIdx.x;
    int lane = tid & 63;
    int wave = tid >> 6;
    int lq   = lane >> 4;
    int lc   = lane & 15;

    int blk  = blockIdx.x;
    int mat  = blk >> 6;               // 0 = P(track), 1 = Q(det)
    int rowg = (blk >> 1) & 31;
    int half = blk & 1;
    int r0   = rowg * 32;
    int h0   = half * 256;
    const float* src = mat ? det : track;

#pragma unroll
    for (int i = 0; i < 4; ++i) {
        int row = wave * 4 + i;
        float4 x = ((const float4*)(src + (size_t)(r0 + row) * E_DIM))[lane];
        float ss = x.x*x.x + x.y*x.y + x.z*x.z + x.w*x.w;
#pragma unroll
        for (int off = 32; off > 0; off >>= 1) ss += __shfl_xor(ss, off);
        if (lane == 0) sclS[row] = 1.0f / fmaxf(sqrtf(ss), 1e-12f);
    }
    __syncthreads();

#pragma unroll
    for (int r = 0; r < 2; ++r) {
        int row = r * 16 + lc;
        float st = sclS[row];
        const float* gp = src + (size_t)(r0 + row) * E_DIM + wave * 32 + lq * 8;
        float4 t0 = *(const float4*)gp;
        float4 t1 = *(const float4*)(gp + 4);
        uint4 v;
        v.x = pkbf(t0.x * st, t0.y * st);
        v.y = pkbf(t0.z * st, t0.w * st);
        v.z = pkbf(t1.x * st, t1.y * st);
        v.w = pkbf(t1.z * st, t1.w * st);
        *(uint4*)&Ash[(size_t)(r * 512 + wave * 64 + lane) * 8] = v;
    }
    __syncthreads();

    const uint4* Wg = (const uint4*)W1cc + (mat ? 16384 : 0);
    int hb = h0 + wave * 32 + lc;
    bf16x8 bwA[2], bwB[2];
#pragma unroll
    for (int ht = 0; ht < 2; ++ht)
        bwA[ht] = __builtin_bit_cast(bf16x8, Wg[(hb + ht * 16) * 4 + lq]);

    f32x4 acc[2][2];
#pragma unroll
    for (int pt = 0; pt < 2; ++pt)
#pragma unroll
        for (int ht = 0; ht < 2; ++ht)
            acc[pt][ht] = (f32x4){0.f, 0.f, 0.f, 0.f};

#pragma unroll 2
    for (int c = 0; c < 8; ++c) {
        bf16x8* cur = (c & 1) ? bwB : bwA;
        bf16x8* nxt = (c & 1) ? bwA : bwB;
        int c1 = (c + 1) & 7;
#pragma unroll
        for (int ht = 0; ht < 2; ++ht)
            nxt[ht] = __builtin_bit_cast(bf16x8, Wg[c1 * 2048 + (hb + ht * 16) * 4 + lq]);
#pragma unroll
        for (int pt = 0; pt < 2; ++pt) {
            bf16x8 af = *(const bf16x8*)&Ash[(size_t)((pt * 8 + c) * 64 + lane) * 8];
#pragma unroll
            for (int ht = 0; ht < 2; ++ht)
                acc[pt][ht] = __builtin_amdgcn_mfma_f32_16x16x32_bf16(cur[ht], af, acc[pt][ht], 0, 0, 0);
        }
    }

    float* dst = mat ? Q : P;
#pragma unroll
    for (int ht = 0; ht < 2; ++ht) {
        int h = h0 + wave * 32 + ht * 16 + lq * 4;
        f32x4 bvv = (f32x4){0.f, 0.f, 0.f, 0.f};
        if (!mat) bvv = *(const f32x4*)&b1[h];
#pragma unroll
        for (int pt = 0; pt < 2; ++pt) {
            f32x4 o = acc[pt][ht] + bvv;
            *(f32x4*)&dst[(size_t)(r0 + pt * 16 + lc) * H_DIM + h] = o;
        }
    }
}

// ---------------- kernel 3: fused pairwise GEMM + LN + SiLU + W2 dot ----------------
// grid 2048 x 512 thr (8 waves). Block: 64 pairs x 512 H; K=256, 8 chunks.
// C layout [h x pair]: A = W1c frags (register dbuf), B = |t-d| frags from LDS.
// P+Q fused into MFMA C-operand. K-loop unroll-2 (ping-pong preserved, bounded liveness).
// Element: pair = pt*16+lc (n=pt*2+(lc>>3), m=lc&7); h = wave*64+ht*16+lq*4+rg.
__global__ __launch_bounds__(512, 4)
void main_kernel(const float* __restrict__ track, const float* __restrict__ det,
                 const __bf16* __restrict__ W1cc,
                 const float* __restrict__ P, const float* __restrict__ Q,
                 const float* __restrict__ gamma, const float* __restrict__ beta,
                 const float* __restrict__ W2, const float* __restrict__ b2,
                 float* __restrict__ out) {
    __shared__ __align__(16) char SMEM[49408];
    __bf16* Ash  = (__bf16*)SMEM;                     // [0,32768) phase 1+2
    float*  tsl  = (float*)(SMEM + 32768);            // 8*TSTR f32, phase 1
    float*  dsl  = (float*)(SMEM + 41088);            // phase 1
    float*  LNr1 = (float*)(SMEM + 32768);            // [64][9] phase 2 (tsl dead)
    float*  LNr2 = (float*)(SMEM + 35072);            // [64][9]
    float*  Red2 = (float*)(SMEM + 37376);            // [64][9]
    float*  MuS  = (float*)(SMEM + 39680);            // [64]
    float*  RsS  = (float*)(SMEM + 39936);            // [64]
    __shared__ float sclT[8], sclD[8];

    int tid  = threadIdx.x;
    int lane = tid & 63;
    int wave = tid >> 6;
    int lq   = lane >> 4;
    int lc   = lane & 15;

    int blk = blockIdx.x;
    int b   = blk >> 8;
    int n0  = ((blk >> 4) & 15) * 8;
    int m0  = (blk & 15) * 8;

    // ---- stage loads: wave w holds row w of t-slice and d-slice
    float4 tstage = ((const float4*)(track + (size_t)(b * 128 + n0 + wave) * E_DIM))[lane];
    float4 dstage = ((const float4*)(det   + (size_t)(b * 128 + m0 + wave) * E_DIM))[lane];

    // ---- W1c frags, chunk-0 prefetch (mat 2 base = 32768 uint4)
    const uint4* Wg = (const uint4*)W1cc + 32768;
    int hb = wave * 64 + lc;
    bf16x8 bwA[4], bwB[4];
#pragma unroll
    for (int ht = 0; ht < 4; ++ht)
        bwA[ht] = __builtin_bit_cast(bf16x8, Wg[(hb + ht * 16) * 4 + lq]);

    // ---- row norms from registers
    {
        float a = tstage.x*tstage.x + tstage.y*tstage.y + tstage.z*tstage.z + tstage.w*tstage.w;
        float d = dstage.x*dstage.x + dstage.y*dstage.y + dstage.z*dstage.z + dstage.w*dstage.w;
#pragma unroll
        for (int off = 32; off > 0; off >>= 1) { a += __shfl_xor(a, off); d += __shfl_xor(d, off); }
        if (lane == 0) {
            sclT[wave] = 1.0f / fmaxf(sqrtf(a), 1e-12f);
            sclD[wave] = 1.0f / fmaxf(sqrtf(d), 1e-12f);
        }
    }
    *(float4*)&tsl[wave * TSTR + lane * 4] = tstage;
    *(float4*)&dsl[wave * TSTR + lane * 4] = dstage;
    __syncthreads();

    // ---- A-stage: iter r covers pair p = r*16+lc, k = wave*32+lq*8 .. +7
    {
        int k0 = wave * 32 + lq * 8;
        int ml = lane & 7;
        float sd = sclD[ml];
        const float* dr = dsl + ml * TSTR + k0;
        float4 d0 = *(const float4*)dr;
        float4 d1 = *(const float4*)(dr + 4);
#pragma unroll
        for (int r = 0; r < 4; ++r) {
            int nl = r * 2 + (lc >> 3);
            float st = sclT[nl];
            const float* tr = tsl + nl * TSTR + k0;
            float4 t0 = *(const float4*)tr;
            float4 t1 = *(const float4*)(tr + 4);
            uint4 v;
            v.x = pkbf(fabsf(t0.x * st - d0.x * sd), fabsf(t0.y * st - d0.y * sd));
            v.y = pkbf(fabsf(t0.z * st - d0.z * sd), fabsf(t0.w * st - d0.w * sd));
            v.z = pkbf(fabsf(t1.x * st - d1.x * sd), fabsf(t1.y * st - d1.y * sd));
            v.w = pkbf(fabsf(t1.z * st - d1.z * sd), fabsf(t1.w * st - d1.w * sd));
            *(uint4*)&Ash[(size_t)(r * 512 + wave * 64 + lane) * 8] = v;
        }
    }

    // ---- C-init: acc = P[n,h] + Q[m,h] (L2-resident, vector f32x4) — fused into MFMA C
    const float* Pb = P + (size_t)(b * 128 + n0) * H_DIM;
    const float* Qb = Q + (size_t)(b * 128 + m0) * H_DIM;
    f32x4 acc[4][4];
    {
        f32x4 qv[4];
#pragma unroll
        for (int ht = 0; ht < 4; ++ht)
            qv[ht] = *(const f32x4*)&Qb[(size_t)(lc & 7) * H_DIM + wave * 64 + ht * 16 + lq * 4];
#pragma unroll
        for (int pt = 0; pt < 4; ++pt) {
            int n = pt * 2 + (lc >> 3);
#pragma unroll
            for (int ht = 0; ht < 4; ++ht) {
                f32x4 pv = *(const f32x4*)&Pb[(size_t)n * H_DIM + wave * 64 + ht * 16 + lq * 4];
                acc[pt][ht] = pv + qv[ht];
            }
        }
    }
    __syncthreads();

    // ---- K-loop: zero barriers; unroll-2 keeps ping-pong dbuf, bounds register liveness
#pragma unroll 2
    for (int c = 0; c < 8; ++c) {
        bf16x8* cur = (c & 1) ? bwB : bwA;
        bf16x8* nxt = (c & 1) ? bwA : bwB;
        int c1 = (c + 1) & 7;
#pragma unroll
        for (int ht = 0; ht < 4; ++ht)
            nxt[ht] = __builtin_bit_cast(bf16x8, Wg[c1 * 2048 + (hb + ht * 16) * 4 + lq]);
#pragma unroll
        for (int pt = 0; pt < 4; ++pt) {
            bf16x8 af = *(const bf16x8*)&Ash[(size_t)((pt * 8 + c) * 64 + lane) * 8];
#pragma unroll
            for (int ht = 0; ht < 4; ++ht)
                acc[pt][ht] = __builtin_amdgcn_mfma_f32_16x16x32_bf16(cur[ht], af, acc[pt][ht], 0, 0, 0);
        }
    }

    // ---- phase B: LN partials: in-register sum over 16 h-values, 2 shuffles across lq
#pragma unroll
    for (int pt = 0; pt < 4; ++pt) {
        float s1 = 0.f, s2 = 0.f;
#pragma unroll
        for (int ht = 0; ht < 4; ++ht)
#pragma unroll
            for (int rg = 0; rg < 4; ++rg) {
                float v = acc[pt][ht][rg];
                s1 += v; s2 += v * v;
            }
        s1 += __shfl_xor(s1, 16); s2 += __shfl_xor(s2, 16);
        s1 += __shfl_xor(s1, 32); s2 += __shfl_xor(s2, 32);
        if (lq == 0) {
            LNr1[(pt * 16 + lc) * 9 + wave] = s1;
            LNr2[(pt * 16 + lc) * 9 + wave] = s2;
        }
    }
    __syncthreads();
    if (tid < 64) {
        float S1 = 0.f, S2 = 0.f;
#pragma unroll
        for (int w = 0; w < 8; ++w) { S1 += LNr1[tid * 9 + w]; S2 += LNr2[tid * 9 + w]; }
        float mu = S1 * (1.0f / 512.0f);
        float var = S2 * (1.0f / 512.0f) - mu * mu;
        MuS[tid] = mu;
        RsS[tid] = rsqrtf(var + 1e-5f);
    }
    __syncthreads();

    // ---- phase C: normalize + SiLU + W2 partial dot (per-ht transient param loads)
    float mus[4], rss[4];
#pragma unroll
    for (int pt = 0; pt < 4; ++pt) { mus[pt] = MuS[pt * 16 + lc]; rss[pt] = RsS[pt * 16 + lc]; }
    float ca[4] = {0.f, 0.f, 0.f, 0.f};
#pragma unroll
    for (int ht = 0; ht < 4; ++ht) {
        int h = wave * 64 + ht * 16 + lq * 4;
        f32x4 g  = *(const f32x4*)&gamma[h];
        f32x4 bb = *(const f32x4*)&beta[h];
        f32x4 w  = *(const f32x4*)&W2[h];
#pragma unroll
        for (int pt = 0; pt < 4; ++pt) {
#pragma unroll
            for (int rg = 0; rg < 4; ++rg) {
                float x = (acc[pt][ht][rg] - mus[pt]) * rss[pt] * g[rg] + bb[rg];
                float sg = __builtin_amdgcn_rcpf(1.0f + __expf(-x));
                ca[pt] += x * sg * w[rg];
            }
        }
    }
#pragma unroll
    for (int pt = 0; pt < 4; ++pt) {
        float c = ca[pt];
        c += __shfl_xor(c, 16);
        c += __shfl_xor(c, 32);
        if (lq == 0) Red2[(pt * 16 + lc) * 9 + wave] = c;
    }
    __syncthreads();
    if (tid < 64) {
        float o = b2[0];
#pragma unroll
        for (int w = 0; w < 8; ++w) o += Red2[tid * 9 + w];
        int n = n0 + (tid >> 3);
        int m = m0 + (tid & 7);
        out[(size_t)(b * 128 + n) * 128 + m] = o;
    }
}

extern "C" void kernel_launch(void* const* d_in, const int* in_sizes, int n_in,
                              void* d_out, int out_size, void* d_ws, size_t ws_size,
                              hipStream_t stream) {
    const float* track = (const float*)d_in[0];
    const float* det   = (const float*)d_in[1];
    const float* W1    = (const float*)d_in[2];
    const float* b1    = (const float*)d_in[3];
    const float* gamma = (const float*)d_in[4];
    const float* beta  = (const float*)d_in[5];
    const float* W2    = (const float*)d_in[6];
    const float* b2    = (const float*)d_in[7];
    float* out = (float*)d_out;

    char* ws = (char*)d_ws;
    float*  P     = (float*)(ws);                      // 2 MB  (1024 x 512 f32)
    float*  Q     = (float*)(ws + (2u << 20));         // 2 MB
    __bf16* W1cc  = (__bf16*)(ws + (4u << 20));        // 768 KB (bf16 chunk-major, 3 mats)

    w1conv_kernel<<<192, 256, 0, stream>>>(W1, W1cc);
    pq_mfma_kernel<<<128, 512, 0, stream>>>(track, det, W1cc, b1, P, Q);
    main_kernel<<<2048, 512, 0, stream>>>(track, det, W1cc, P, Q, gamma, beta, W2, b2, out);
}